// Round 1
// baseline (121.096 us; speedup 1.0000x reference)
//
#include <hip/hip_runtime.h>
#include <cmath>

// h_t = lam*(x_t + h_{t-1}) + b ; out_t = h_t^2 * sigmoid(h_t)
// Outputs (concat flat): output [T,B,D] then h [T+1,B,D] (h[0]=h0).
// Linear recurrence -> chunked scan over T: 3 passes.

__device__ __forceinline__ float sigmoid_fast(float v) {
    return 1.0f / (1.0f + __expf(-v));
}

// Pass 1: per-(chunk, col) local scan seeded with 0; store chunk-end value.
__global__ void rnn_pass1(const float* __restrict__ x, const float* __restrict__ b,
                          const float* __restrict__ ll, float* __restrict__ Send,
                          int T, int BD, int D, int L, int nColBlk)
{
    int cb = blockIdx.x % nColBlk;
    int k  = blockIdx.x / nColBlk;
    int c4 = cb * blockDim.x + threadIdx.x;
    int col = c4 * 4;
    if (col >= BD) return;
    float lam = 1.0f / (1.0f + expf(-ll[0]));
    const float4 bb = *reinterpret_cast<const float4*>(b + (col % D));
    float4 h = make_float4(0.f, 0.f, 0.f, 0.f);
    int t0 = k * L;
    int t1 = min(T, t0 + L);
    const float* xp = x + (size_t)t0 * BD + col;
#pragma unroll 4
    for (int t = t0; t < t1; ++t, xp += BD) {
        float4 xv = *reinterpret_cast<const float4*>(xp);
        h.x = lam * (xv.x + h.x) + bb.x;
        h.y = lam * (xv.y + h.y) + bb.y;
        h.z = lam * (xv.z + h.z) + bb.z;
        h.w = lam * (xv.w + h.w) + bb.w;
    }
    *reinterpret_cast<float4*>(Send + (size_t)k * BD + col) = h;
}

// Pass 2: sequential combine over chunks per column chain.
// carry[k] = h value entering chunk k (i.e. h_{k*L - 1}, with carry[0] = h0).
__global__ void rnn_pass2(const float* __restrict__ h0, const float* __restrict__ ll,
                          const float* __restrict__ Send, float* __restrict__ carry,
                          float* __restrict__ hout0, int T, int BD, int L, int C)
{
    int col = blockIdx.x * blockDim.x + threadIdx.x;
    if (col >= BD) return;
    float lam = 1.0f / (1.0f + expf(-ll[0]));
    float H = h0[col];
    hout0[col] = H;  // h[0] = h0
    for (int k = 0; k < C; ++k) {
        carry[(size_t)k * BD + col] = H;
        int t0 = k * L;
        int t1 = min(T, t0 + L);
        float A = powf(lam, (float)(t1 - t0));
        H = A * H + Send[(size_t)k * BD + col];
    }
}

// Pass 3: exact recurrence seeded with carry; write output and h.
__global__ void rnn_pass3(const float* __restrict__ x, const float* __restrict__ b,
                          const float* __restrict__ ll, const float* __restrict__ carry,
                          float* __restrict__ out, float* __restrict__ hout,
                          int T, int BD, int D, int L, int nColBlk)
{
    int cb = blockIdx.x % nColBlk;
    int k  = blockIdx.x / nColBlk;
    int c4 = cb * blockDim.x + threadIdx.x;
    int col = c4 * 4;
    if (col >= BD) return;
    float lam = 1.0f / (1.0f + expf(-ll[0]));
    const float4 bb = *reinterpret_cast<const float4*>(b + (col % D));
    float4 h = *reinterpret_cast<const float4*>(carry + (size_t)k * BD + col);
    int t0 = k * L;
    int t1 = min(T, t0 + L);
    const float* xp = x + (size_t)t0 * BD + col;
    float* op = out + (size_t)t0 * BD + col;
    float* hp = hout + (size_t)(t0 + 1) * BD + col;  // h[t+1] = h_t
#pragma unroll 4
    for (int t = t0; t < t1; ++t, xp += BD, op += BD, hp += BD) {
        float4 xv = *reinterpret_cast<const float4*>(xp);
        h.x = lam * (xv.x + h.x) + bb.x;
        h.y = lam * (xv.y + h.y) + bb.y;
        h.z = lam * (xv.z + h.z) + bb.z;
        h.w = lam * (xv.w + h.w) + bb.w;
        float4 o;
        o.x = h.x * h.x * sigmoid_fast(h.x);
        o.y = h.y * h.y * sigmoid_fast(h.y);
        o.z = h.z * h.z * sigmoid_fast(h.z);
        o.w = h.w * h.w * sigmoid_fast(h.w);
        *reinterpret_cast<float4*>(op) = o;
        *reinterpret_cast<float4*>(hp) = h;
    }
}

// Fallback if d_ws is too small for even one chunk of scratch: fully fused,
// one thread per 4 columns runs the whole T sequentially (low parallelism).
__global__ void rnn_fused(const float* __restrict__ x, const float* __restrict__ b,
                          const float* __restrict__ ll, const float* __restrict__ h0,
                          float* __restrict__ out, float* __restrict__ hout,
                          int T, int BD, int D)
{
    int c4 = blockIdx.x * blockDim.x + threadIdx.x;
    int col = c4 * 4;
    if (col >= BD) return;
    float lam = 1.0f / (1.0f + expf(-ll[0]));
    const float4 bb = *reinterpret_cast<const float4*>(b + (col % D));
    float4 h = *reinterpret_cast<const float4*>(h0 + col);
    *reinterpret_cast<float4*>(hout + col) = h;
    const float* xp = x + col;
    float* op = out + col;
    float* hp = hout + (size_t)BD + col;
#pragma unroll 4
    for (int t = 0; t < T; ++t, xp += BD, op += BD, hp += BD) {
        float4 xv = *reinterpret_cast<const float4*>(xp);
        h.x = lam * (xv.x + h.x) + bb.x;
        h.y = lam * (xv.y + h.y) + bb.y;
        h.z = lam * (xv.z + h.z) + bb.z;
        h.w = lam * (xv.w + h.w) + bb.w;
        float4 o;
        o.x = h.x * h.x * sigmoid_fast(h.x);
        o.y = h.y * h.y * sigmoid_fast(h.y);
        o.z = h.z * h.z * sigmoid_fast(h.z);
        o.w = h.w * h.w * sigmoid_fast(h.w);
        *reinterpret_cast<float4*>(op) = o;
        *reinterpret_cast<float4*>(hp) = h;
    }
}

extern "C" void kernel_launch(void* const* d_in, const int* in_sizes, int n_in,
                              void* d_out, int out_size, void* d_ws, size_t ws_size,
                              hipStream_t stream) {
    const float* x  = (const float*)d_in[0];
    const float* ll = (const float*)d_in[1];
    const float* b  = (const float*)d_in[2];
    const float* h0 = (const float*)d_in[3];

    const int D  = in_sizes[2];      // 2048
    const int BD = in_sizes[3];      // B*D = 16384
    const int T  = in_sizes[0] / BD; // 2048

    float* out  = (float*)d_out;                 // [T, B*D]
    float* hout = out + (size_t)T * BD;          // [(T+1), B*D]

    const int threads = 256;
    const int nColBlk = (BD / 4 + threads - 1) / threads; // 16

    // Choose chunk count C so scratch (2 * C * BD floats) fits in d_ws.
    int C = 64;
    while (C > 1 && (size_t)2 * C * BD * sizeof(float) > ws_size) C >>= 1;

    if ((size_t)2 * C * BD * sizeof(float) > ws_size) {
        // No usable scratch: fully sequential fused kernel.
        rnn_fused<<<nColBlk, threads, 0, stream>>>(x, b, ll, h0, out, hout, T, BD, D);
        return;
    }

    int L = (T + C - 1) / C;
    C = (T + L - 1) / L;  // drop empty chunks

    float* Send  = (float*)d_ws;
    float* carry = Send + (size_t)C * BD;

    rnn_pass1<<<dim3(nColBlk * C), threads, 0, stream>>>(x, b, ll, Send, T, BD, D, L, nColBlk);
    rnn_pass2<<<dim3((BD + threads - 1) / threads), threads, 0, stream>>>(h0, ll, Send, carry, hout, T, BD, L, C);
    rnn_pass3<<<dim3(nColBlk * C), threads, 0, stream>>>(x, b, ll, carry, out, hout, T, BD, D, L, nColBlk);
}

// Round 2
// 104.199 us; speedup vs baseline: 1.1622x; 1.1622x over previous
//
#include <hip/hip_runtime.h>
#include <cmath>

// h_t = lam*(x_t + h_{t-1}) + b ; out_t = h_t^2 * sigmoid(h_t)
// Outputs (concat flat): output [T,B,D] then h [T+1,B,D] (h[0]=h0).
//
// Single-pass chunked kernel: lam = sigmoid(log_lambda) < 1, so the entering
// state of a chunk can be reconstructed by a W-step warm-up from h=0 with
// error lam^W * |h|. W is computed on-device from lam (W = ceil(ln(eps)/ln(lam)),
// clamped to s0) -> exact fallback for lam -> 1, negligible error (~1e-9) for
// the moderate-lam regime. One read of x, one write of out and h. No scratch.

__global__ __launch_bounds__(256) void rnn_onepass(
    const float* __restrict__ x, const float* __restrict__ ll,
    const float* __restrict__ b, const float* __restrict__ h0,
    float* __restrict__ out, float* __restrict__ hout,
    int T, int BD, int D, int S, int nColBlk)
{
    const int cb = blockIdx.x % nColBlk;
    const int k  = blockIdx.x / nColBlk;
    const int col = (cb * blockDim.x + threadIdx.x) * 2;
    if (col >= BD) return;

    const float lam = 1.0f / (1.0f + __expf(-ll[0]));
    const float2 bb = *reinterpret_cast<const float2*>(b + (col % D));

    const int s0 = k * S;
    const int s1 = min(T, s0 + S);

    float2 h;
    int W = 0;
    if (k == 0) {
        h = *reinterpret_cast<const float2*>(h0 + col);
        // h[0] = h0 (only the k==0 column-blocks cover this row, once each)
        *reinterpret_cast<float2*>(hout + col) = h;
    } else {
        h = make_float2(0.f, 0.f);
        // warm-up length: lam^W <= 1e-9  (clamped so lam->1 degrades to exact)
        float l = fminf(fmaxf(lam, 1e-12f), 1.0f - 1e-7f);
        float Wf = ceilf(logf(1e-9f) / logf(l));
        W = (Wf < (float)s0) ? max(1, (int)Wf) : s0;
    }

    const float* xp = x + (size_t)(s0 - W) * BD + col;
    for (int t = s0 - W; t < s0; ++t, xp += BD) {
        float2 xv = *reinterpret_cast<const float2*>(xp);
        h.x = lam * (xv.x + h.x) + bb.x;
        h.y = lam * (xv.y + h.y) + bb.y;
    }

    float* op = out  + (size_t)s0 * BD + col;
    float* hp = hout + (size_t)(s0 + 1) * BD + col;  // h[t+1] = h_t
#pragma unroll 4
    for (int t = s0; t < s1; ++t, xp += BD, op += BD, hp += BD) {
        float2 xv = *reinterpret_cast<const float2*>(xp);
        h.x = lam * (xv.x + h.x) + bb.x;
        h.y = lam * (xv.y + h.y) + bb.y;
        float2 o;
        o.x = h.x * h.x * __builtin_amdgcn_rcpf(1.0f + __expf(-h.x));
        o.y = h.y * h.y * __builtin_amdgcn_rcpf(1.0f + __expf(-h.y));
        *reinterpret_cast<float2*>(op) = o;
        *reinterpret_cast<float2*>(hp) = h;
    }
}

extern "C" void kernel_launch(void* const* d_in, const int* in_sizes, int n_in,
                              void* d_out, int out_size, void* d_ws, size_t ws_size,
                              hipStream_t stream) {
    const float* x  = (const float*)d_in[0];
    const float* ll = (const float*)d_in[1];
    const float* b  = (const float*)d_in[2];
    const float* h0 = (const float*)d_in[3];

    const int D  = in_sizes[2];      // 2048
    const int BD = in_sizes[3];      // B*D = 16384
    const int T  = in_sizes[0] / BD; // 2048

    float* out  = (float*)d_out;                 // [T, B*D]
    float* hout = out + (size_t)T * BD;          // [(T+1), B*D]

    const int threads = 256;
    const int S = 128;                                   // chunk length
    const int C = (T + S - 1) / S;                       // 16 chunks
    const int nColBlk = (BD / 2 + threads - 1) / threads; // 32 col-blocks

    rnn_onepass<<<dim3(nColBlk * C), threads, 0, stream>>>(
        x, ll, b, h0, out, hout, T, BD, D, S, nColBlk);
}

// Round 4
// 85.929 us; speedup vs baseline: 1.4093x; 1.2126x over previous
//
#include <hip/hip_runtime.h>
#include <cmath>

// h_t = lam*(x_t + h_{t-1}) + b ; out_t = h_t^2 * sigmoid(h_t)
// Outputs (concat flat): output [T,B,D] then h [T+1,B,D] (h[0]=h0).
//
// Single-pass chunked kernel with decay warm-up:
//   lam = sigmoid(log_lambda) < 1, so a chunk's entering state is
//   reconstructed by a W-step warm-up from h=0 with error lam^W*|h|.
//   W computed on-device (clamped to s0 -> exact fallback as lam -> 1).
// float4 (ext_vector_type, 16B) lanes; chain shortened to one fma
// (h = fma(lam,h, fma(lam,x,b))); nontemporal stores for out/h so x
// stays L3-resident across warm-up reads and graph replays.

typedef float f4 __attribute__((ext_vector_type(4)));

__global__ __launch_bounds__(256) void rnn_onepass(
    const float* __restrict__ x, const float* __restrict__ ll,
    const float* __restrict__ b, const float* __restrict__ h0,
    float* __restrict__ out, float* __restrict__ hout,
    int T, int BD, int D, int S, int nColBlk)
{
    const int cb = blockIdx.x % nColBlk;
    const int k  = blockIdx.x / nColBlk;
    const int col = (cb * blockDim.x + threadIdx.x) * 4;
    if (col >= BD) return;

    const float lam = 1.0f / (1.0f + __expf(-ll[0]));
    const f4 bb = *reinterpret_cast<const f4*>(b + (col % D));

    const int s0 = k * S;
    const int s1 = min(T, s0 + S);

    f4 h;
    int W = 0;
    if (k == 0) {
        h = *reinterpret_cast<const f4*>(h0 + col);
        // h[0] = h0 (covered once, by the k==0 column-blocks)
        __builtin_nontemporal_store(h, reinterpret_cast<f4*>(hout + col));
    } else {
        h = (f4)(0.f);
        // warm-up length: lam^W <= 1e-9 (clamped so lam->1 degrades to exact)
        float l = fminf(fmaxf(lam, 1e-12f), 1.0f - 1e-7f);
        float Wf = ceilf(logf(1e-9f) / logf(l));
        W = (Wf < (float)s0) ? max(1, (int)Wf) : s0;
    }

    const float* xp = x + (size_t)(s0 - W) * BD + col;
    for (int t = s0 - W; t < s0; ++t, xp += BD) {
        f4 xv = *reinterpret_cast<const f4*>(xp);
        h.x = __builtin_fmaf(lam, h.x, __builtin_fmaf(lam, xv.x, bb.x));
        h.y = __builtin_fmaf(lam, h.y, __builtin_fmaf(lam, xv.y, bb.y));
        h.z = __builtin_fmaf(lam, h.z, __builtin_fmaf(lam, xv.z, bb.z));
        h.w = __builtin_fmaf(lam, h.w, __builtin_fmaf(lam, xv.w, bb.w));
    }

    float* op = out  + (size_t)s0 * BD + col;
    float* hp = hout + (size_t)(s0 + 1) * BD + col;  // h[t+1] = h_t
#pragma unroll 4
    for (int t = s0; t < s1; ++t, xp += BD, op += BD, hp += BD) {
        f4 xv = *reinterpret_cast<const f4*>(xp);
        h.x = __builtin_fmaf(lam, h.x, __builtin_fmaf(lam, xv.x, bb.x));
        h.y = __builtin_fmaf(lam, h.y, __builtin_fmaf(lam, xv.y, bb.y));
        h.z = __builtin_fmaf(lam, h.z, __builtin_fmaf(lam, xv.z, bb.z));
        h.w = __builtin_fmaf(lam, h.w, __builtin_fmaf(lam, xv.w, bb.w));
        f4 o;
        o.x = h.x * h.x * __builtin_amdgcn_rcpf(1.0f + __expf(-h.x));
        o.y = h.y * h.y * __builtin_amdgcn_rcpf(1.0f + __expf(-h.y));
        o.z = h.z * h.z * __builtin_amdgcn_rcpf(1.0f + __expf(-h.z));
        o.w = h.w * h.w * __builtin_amdgcn_rcpf(1.0f + __expf(-h.w));
        __builtin_nontemporal_store(o, reinterpret_cast<f4*>(op));
        __builtin_nontemporal_store(h, reinterpret_cast<f4*>(hp));
    }
}

extern "C" void kernel_launch(void* const* d_in, const int* in_sizes, int n_in,
                              void* d_out, int out_size, void* d_ws, size_t ws_size,
                              hipStream_t stream) {
    const float* x  = (const float*)d_in[0];
    const float* ll = (const float*)d_in[1];
    const float* b  = (const float*)d_in[2];
    const float* h0 = (const float*)d_in[3];

    const int D  = in_sizes[2];      // 2048
    const int BD = in_sizes[3];      // B*D = 16384
    const int T  = in_sizes[0] / BD; // 2048

    float* out  = (float*)d_out;                 // [T, B*D]
    float* hout = out + (size_t)T * BD;          // [(T+1), B*D]

    const int threads = 256;
    const int S = 64;                                     // chunk length
    const int C = (T + S - 1) / S;                        // 32 chunks
    const int nColBlk = (BD / 4 + threads - 1) / threads; // 16 col-blocks

    rnn_onepass<<<dim3(nColBlk * C), threads, 0, stream>>>(
        x, ll, b, h0, out, hout, T, BD, D, S, nColBlk);
}

// Round 5
// 66.951 us; speedup vs baseline: 1.8087x; 1.2835x over previous
//
#include <hip/hip_runtime.h>
#include <cmath>

// h_t = lam*(x_t + h_{t-1}) + b ; out_t = h_t^2 * sigmoid(h_t)
// Outputs (concat flat): output [T,B,D] then h [T+1,B,D] (h[0]=h0).
//
// Block-parallel scan kernel:
//   Each block: 256 timesteps x 64 columns. Each thread: 16 rows of one f4
//   column held in registers. Seed-0 local scan -> LDS Hillis-Steele scan
//   (weight lam^16) across 16 thread-groups -> per-thread seed.
//   Block-entering state via parallel warm-up sum over W = ceil(ln eps/ln lam)
//   preceding rows (clamped to t0; the lam^W*h0 tail makes the clamped case
//   exact, and naturally yields H=h0 for the t0==0 block).

typedef float f4 __attribute__((ext_vector_type(4)));

__device__ __forceinline__ f4 vfma(float a, f4 v, f4 c) {
    f4 r;
    r.x = __builtin_fmaf(a, v.x, c.x);
    r.y = __builtin_fmaf(a, v.y, c.y);
    r.z = __builtin_fmaf(a, v.z, c.z);
    r.w = __builtin_fmaf(a, v.w, c.w);
    return r;
}

#define TS 256   // timesteps per block
#define G  16    // thread t-groups per block
#define TT 16    // timesteps per thread (TS/G)
#define C4 16    // f4 column-groups per block (64 float columns)

__global__ __launch_bounds__(256) void rnn_scan(
    const float* __restrict__ x, const float* __restrict__ ll,
    const float* __restrict__ b, const float* __restrict__ h0,
    float* __restrict__ out, float* __restrict__ hout,
    int T, int BD, int D, int nColBlk)
{
    __shared__ f4 lds[G][C4];   // [g][c]: row stride 256B -> 2-way alias (free)

    const int tid = threadIdx.x;
    const int c   = tid % C4;
    const int g   = tid / C4;
    const int cb  = blockIdx.x % nColBlk;
    const int tb  = blockIdx.x / nColBlk;
    const int col = cb * (C4 * 4) + c * 4;
    const int t0  = tb * TS;

    const float lam = 1.0f / (1.0f + __expf(-ll[0]));
    const f4 bb = *reinterpret_cast<const f4*>(b + (col % D));
    const float A0 = __powf(lam, 16.0f);   // lam^16 (= lam^G = lam^TT)

    // ---- phase A: load x tile into regs ----
    f4 xr[TT];
    const float* xbase = x + (size_t)(t0 + g * TT) * BD + col;
#pragma unroll
    for (int i = 0; i < TT; ++i)
        xr[i] = *reinterpret_cast<const f4*>(xbase + (size_t)i * BD);

    // ---- parallel warm-up: H_enter = h_{t0-1} ----
    // = sum_{j=0}^{W-1} lam^{j+1} x[t0-1-j]  +  b*(1-lam^W)/(1-lam)
    //   + (W==t0 ? lam^W * h0 : ~0)
    const float l = fminf(fmaxf(lam, 1e-12f), 1.0f - 1e-7f);
    const int Wf = (int)ceilf(logf(1e-9f) / logf(l));
    const int W  = min(Wf, t0);

    f4 part = (f4)(0.0f);
    if (W > 0) {
        float w = __powf(lam, (float)(g + 1));
        const float* wp = x + (size_t)(t0 - 1 - g) * BD + col;
        for (int j = g; j < W; j += G) {
            f4 xv = *reinterpret_cast<const f4*>(wp);
            part = vfma(w, xv, part);
            w *= A0;
            wp -= (size_t)G * BD;
        }
    }
    lds[g][c] = part;
    __syncthreads();
#pragma unroll
    for (int off = G / 2; off > 0; off >>= 1) {
        if (g < off) lds[g][c] += lds[g + off][c];
        __syncthreads();
    }
    f4 Hent = lds[0][c];

    const float one_m = 1.0f - lam;
    const float lamW  = __powf(lam, (float)W);
    const float gsum  = (one_m > 1e-6f) ? (1.0f - lamW) / one_m : (float)W;
    Hent = vfma(gsum, bb, Hent);
    if (W == t0) {   // clamped (or t0==0): add exact lam^W * h0 tail
        f4 h0v = *reinterpret_cast<const f4*>(h0 + col);
        Hent = vfma(lamW, h0v, Hent);
        if (t0 == 0 && g == 0)   // h[0] = h0, written once per column
            __builtin_nontemporal_store(h0v, reinterpret_cast<f4*>(hout + col));
    }
    __syncthreads();   // before reusing lds

    // ---- local seed-0 scan over this thread's 16 rows ----
    f4 e = (f4)(0.0f);
#pragma unroll
    for (int i = 0; i < TT; ++i)
        e = vfma(lam, xr[i] + e, bb);   // e = lam*(x+e)+b

    lds[g][c] = e;
    __syncthreads();

    // ---- weighted Hillis-Steele inclusive scan over g (weight lam^16/step) ----
    float Aw = A0;
    for (int d = 1; d < G; d <<= 1) {
        f4 t = (g >= d) ? lds[g - d][c] : (f4)(0.0f);
        __syncthreads();
        lds[g][c] = vfma(Aw, t, lds[g][c]);
        __syncthreads();
        Aw *= Aw;
    }

    // entering state for this thread's group
    f4 ent = (g > 0) ? lds[g - 1][c] : (f4)(0.0f);
    ent = vfma(__powf(lam, (float)(g * TT)), Hent, ent);

    // ---- phase B: exact recurrence from seed, write out + h ----
    f4 h = ent;
    float* op = out  + (size_t)(t0 + g * TT) * BD + col;
    float* hp = hout + (size_t)(t0 + g * TT + 1) * BD + col;
#pragma unroll
    for (int i = 0; i < TT; ++i, op += BD, hp += BD) {
        h = vfma(lam, xr[i] + h, bb);
        f4 o;
        o.x = h.x * h.x * __builtin_amdgcn_rcpf(1.0f + __expf(-h.x));
        o.y = h.y * h.y * __builtin_amdgcn_rcpf(1.0f + __expf(-h.y));
        o.z = h.z * h.z * __builtin_amdgcn_rcpf(1.0f + __expf(-h.z));
        o.w = h.w * h.w * __builtin_amdgcn_rcpf(1.0f + __expf(-h.w));
        __builtin_nontemporal_store(o, reinterpret_cast<f4*>(op));
        __builtin_nontemporal_store(h, reinterpret_cast<f4*>(hp));
    }
}

// ---- fallback (R4 kernel) for shapes not divisible by the tile ----
__global__ __launch_bounds__(256) void rnn_onepass(
    const float* __restrict__ x, const float* __restrict__ ll,
    const float* __restrict__ b, const float* __restrict__ h0,
    float* __restrict__ out, float* __restrict__ hout,
    int T, int BD, int D, int S, int nColBlk)
{
    const int cb = blockIdx.x % nColBlk;
    const int k  = blockIdx.x / nColBlk;
    const int col = (cb * blockDim.x + threadIdx.x) * 4;
    if (col >= BD) return;

    const float lam = 1.0f / (1.0f + __expf(-ll[0]));
    const f4 bb = *reinterpret_cast<const f4*>(b + (col % D));
    const int s0 = k * S;
    const int s1 = min(T, s0 + S);

    f4 h;
    int W = 0;
    if (k == 0) {
        h = *reinterpret_cast<const f4*>(h0 + col);
        __builtin_nontemporal_store(h, reinterpret_cast<f4*>(hout + col));
    } else {
        h = (f4)(0.f);
        float l = fminf(fmaxf(lam, 1e-12f), 1.0f - 1e-7f);
        float Wff = ceilf(logf(1e-9f) / logf(l));
        W = (Wff < (float)s0) ? max(1, (int)Wff) : s0;
    }

    const float* xp = x + (size_t)(s0 - W) * BD + col;
    for (int t = s0 - W; t < s0; ++t, xp += BD) {
        f4 xv = *reinterpret_cast<const f4*>(xp);
        h = vfma(lam, xv + h, bb);
    }

    float* op = out  + (size_t)s0 * BD + col;
    float* hp = hout + (size_t)(s0 + 1) * BD + col;
#pragma unroll 4
    for (int t = s0; t < s1; ++t, xp += BD, op += BD, hp += BD) {
        f4 xv = *reinterpret_cast<const f4*>(xp);
        h = vfma(lam, xv + h, bb);
        f4 o;
        o.x = h.x * h.x * __builtin_amdgcn_rcpf(1.0f + __expf(-h.x));
        o.y = h.y * h.y * __builtin_amdgcn_rcpf(1.0f + __expf(-h.y));
        o.z = h.z * h.z * __builtin_amdgcn_rcpf(1.0f + __expf(-h.z));
        o.w = h.w * h.w * __builtin_amdgcn_rcpf(1.0f + __expf(-h.w));
        __builtin_nontemporal_store(o, reinterpret_cast<f4*>(op));
        __builtin_nontemporal_store(h, reinterpret_cast<f4*>(hp));
    }
}

extern "C" void kernel_launch(void* const* d_in, const int* in_sizes, int n_in,
                              void* d_out, int out_size, void* d_ws, size_t ws_size,
                              hipStream_t stream) {
    const float* x  = (const float*)d_in[0];
    const float* ll = (const float*)d_in[1];
    const float* b  = (const float*)d_in[2];
    const float* h0 = (const float*)d_in[3];

    const int D  = in_sizes[2];      // 2048
    const int BD = in_sizes[3];      // B*D = 16384
    const int T  = in_sizes[0] / BD; // 2048

    float* out  = (float*)d_out;                 // [T, B*D]
    float* hout = out + (size_t)T * BD;          // [(T+1), B*D]

    const int COLS = C4 * 4;  // 64 columns per block
    if (T % TS == 0 && BD % COLS == 0 && D % COLS == 0) {
        const int nColBlk = BD / COLS;       // 256
        const int nTb = T / TS;              // 8
        rnn_scan<<<dim3(nColBlk * nTb), 256, 0, stream>>>(
            x, ll, b, h0, out, hout, T, BD, D, nColBlk);
    } else {
        const int threads = 256;
        const int S = 64;
        const int C = (T + S - 1) / S;
        const int nColBlk = (BD / 4 + threads - 1) / threads;
        rnn_onepass<<<dim3(nColBlk * C), threads, 0, stream>>>(
            x, ll, b, h0, out, hout, T, BD, D, S, nColBlk);
    }
}